// Round 1
// baseline (2121.840 us; speedup 1.0000x reference)
//
#include <hip/hip_runtime.h>
#include <hip/hip_bf16.h>

#define KB 5
#define NH 10
#define BN_EPS 1e-5f

__device__ __forceinline__ float sigmoidf_fast(float z) {
    // sigmoid(z) = 1 / (1 + exp(-z)) ; exp(-z) = exp2(-z*log2(e))
    float e = __builtin_amdgcn_exp2f(-1.442695040888963f * z);
    return __builtin_amdgcn_rcpf(1.0f + e);
}

__device__ __forceinline__ float tanhf_fast(float z) {
    // tanh(z) = 1 - 2/(exp(2z)+1); exp(2z) = exp2(2z*log2(e))
    float e = __builtin_amdgcn_exp2f(2.885390081777927f * z);
    return 1.0f - 2.0f * __builtin_amdgcn_rcpf(e + 1.0f);
    // z->+inf: e=inf -> rcp=0 -> 1 ; z->-inf: e=0 -> -1  (correct limits)
}

__device__ __forceinline__ void compute_a1(float xv, float yv, float tv,
                                           const float* __restrict__ W1,
                                           const float* __restrict__ b1,
                                           int k, float* a1) {
    #pragma unroll
    for (int n = 0; n < NH; n++) {
        const float* w = W1 + (k * NH + n) * 3;
        float z = fmaf(w[0], xv, fmaf(w[1], yv, fmaf(w[2], tv, b1[k * NH + n])));
        a1[n] = sigmoidf_fast(z);
    }
}

// ---------------- pass 1: stats of a1 = sigmoid(W1*in + b1) ----------------
__global__ __launch_bounds__(256) void pass1_stats(
    const float* __restrict__ x, const float* __restrict__ y, const float* __restrict__ t,
    const float* __restrict__ W1, const float* __restrict__ b1,
    float* __restrict__ stats1, int B) {
    float s[KB * NH], q[KB * NH];
    #pragma unroll
    for (int v = 0; v < KB * NH; v++) { s[v] = 0.f; q[v] = 0.f; }

    int stride = gridDim.x * blockDim.x;
    #pragma unroll 1
    for (int i = blockIdx.x * blockDim.x + threadIdx.x; i < B; i += stride) {
        float xv = x[i], yv = y[i], tv = t[i];
        #pragma unroll
        for (int k = 0; k < KB; k++) {
            #pragma unroll
            for (int n = 0; n < NH; n++) {
                const float* w = W1 + (k * NH + n) * 3;
                float z = fmaf(w[0], xv, fmaf(w[1], yv, fmaf(w[2], tv, b1[k * NH + n])));
                float a = sigmoidf_fast(z);
                s[k * NH + n] += a;
                q[k * NH + n] = fmaf(a, a, q[k * NH + n]);
            }
        }
    }
    // wave-level butterfly reduce, one atomic per wave per value
    #pragma unroll
    for (int v = 0; v < KB * NH; v++) {
        float sv = s[v], qv = q[v];
        #pragma unroll
        for (int o = 32; o > 0; o >>= 1) {
            sv += __shfl_xor(sv, o);
            qv += __shfl_xor(qv, o);
        }
        if ((threadIdx.x & 63) == 0) {
            atomicAdd(&stats1[v], sv);
            atomicAdd(&stats1[KB * NH + v], qv);
        }
    }
}

// ---------------- fold 1: BN1 folded into W2 -> W2f, b2f ----------------
__global__ void fold1(const float* __restrict__ stats1,
                      const float* __restrict__ g1, const float* __restrict__ be1,
                      const float* __restrict__ W2, const float* __restrict__ b2,
                      float* __restrict__ W2f, float* __restrict__ b2f, float invB) {
    __shared__ float alpha[KB * NH], beta[KB * NH];
    int tid = threadIdx.x;
    if (tid < KB * NH) {
        float m = stats1[tid] * invB;
        float var = stats1[KB * NH + tid] * invB - m * m;
        float rstd = rsqrtf(var + BN_EPS);
        float a = g1[tid] * rstd;
        alpha[tid] = a;
        beta[tid] = be1[tid] - a * m;
    }
    __syncthreads();
    if (tid < KB * NH) {  // tid = k*NH + m
        int k = tid / NH;
        float acc = b2[tid];
        #pragma unroll
        for (int n = 0; n < NH; n++) {
            float w = W2[tid * NH + n];
            W2f[tid * NH + n] = w * alpha[k * NH + n];
            acc = fmaf(w, beta[k * NH + n], acc);
        }
        b2f[tid] = acc;
    }
}

// ---------------- pass 2: stats of a2 = sigmoid(W2f*a1 + b2f) ----------------
__global__ __launch_bounds__(256) void pass2_stats(
    const float* __restrict__ x, const float* __restrict__ y, const float* __restrict__ t,
    const float* __restrict__ W1, const float* __restrict__ b1,
    const float* __restrict__ W2f, const float* __restrict__ b2f,
    float* __restrict__ stats2, int B) {
    float s[KB * NH], q[KB * NH];
    #pragma unroll
    for (int v = 0; v < KB * NH; v++) { s[v] = 0.f; q[v] = 0.f; }

    int stride = gridDim.x * blockDim.x;
    #pragma unroll 1
    for (int i = blockIdx.x * blockDim.x + threadIdx.x; i < B; i += stride) {
        float xv = x[i], yv = y[i], tv = t[i];
        #pragma unroll
        for (int k = 0; k < KB; k++) {
            float a1[NH];
            compute_a1(xv, yv, tv, W1, b1, k, a1);
            #pragma unroll
            for (int m = 0; m < NH; m++) {
                float z = b2f[k * NH + m];
                #pragma unroll
                for (int n = 0; n < NH; n++)
                    z = fmaf(W2f[(k * NH + m) * NH + n], a1[n], z);
                float a = sigmoidf_fast(z);
                s[k * NH + m] += a;
                q[k * NH + m] = fmaf(a, a, q[k * NH + m]);
            }
        }
    }
    #pragma unroll
    for (int v = 0; v < KB * NH; v++) {
        float sv = s[v], qv = q[v];
        #pragma unroll
        for (int o = 32; o > 0; o >>= 1) {
            sv += __shfl_xor(sv, o);
            qv += __shfl_xor(qv, o);
        }
        if ((threadIdx.x & 63) == 0) {
            atomicAdd(&stats2[v], sv);
            atomicAdd(&stats2[KB * NH + v], qv);
        }
    }
}

// ---------------- fold 2: BN2 folded into W3 -> W3f, b3f ----------------
__global__ void fold2(const float* __restrict__ stats2,
                      const float* __restrict__ g2, const float* __restrict__ be2,
                      const float* __restrict__ W3, const float* __restrict__ b3,
                      float* __restrict__ W3f, float* __restrict__ b3f, float invB) {
    __shared__ float beta[KB * NH];
    int tid = threadIdx.x;
    if (tid < KB * NH) {
        float m = stats2[tid] * invB;
        float var = stats2[KB * NH + tid] * invB - m * m;
        float rstd = rsqrtf(var + BN_EPS);
        float al = g2[tid] * rstd;
        beta[tid] = be2[tid] - al * m;
        W3f[tid] = W3[tid] * al;   // W3 is [K,1,N] -> flat [K*N]
    }
    __syncthreads();
    if (tid < KB) {
        float acc = b3[tid];
        #pragma unroll
        for (int n = 0; n < NH; n++)
            acc = fmaf(W3[tid * NH + n], beta[tid * NH + n], acc);
        b3f[tid] = acc;
    }
}

// ---------------- pass 3: full forward + output ----------------
__global__ __launch_bounds__(256) void pass3_out(
    const float* __restrict__ x, const float* __restrict__ y, const float* __restrict__ t,
    const float* __restrict__ W1, const float* __restrict__ b1,
    const float* __restrict__ W2f, const float* __restrict__ b2f,
    const float* __restrict__ W3f, const float* __restrict__ b3f,
    float* __restrict__ out, int B) {
    int stride = gridDim.x * blockDim.x;
    #pragma unroll 1
    for (int i = blockIdx.x * blockDim.x + threadIdx.x; i < B; i += stride) {
        float xv = x[i], yv = y[i], tv = t[i];
        #pragma unroll
        for (int k = 0; k < KB; k++) {
            float a1[NH];
            compute_a1(xv, yv, tv, W1, b1, k, a1);
            float a2[NH];
            #pragma unroll
            for (int m = 0; m < NH; m++) {
                float z = b2f[k * NH + m];
                #pragma unroll
                for (int n = 0; n < NH; n++)
                    z = fmaf(W2f[(k * NH + m) * NH + n], a1[n], z);
                a2[m] = sigmoidf_fast(z);
            }
            float o = b3f[k];
            #pragma unroll
            for (int n = 0; n < NH; n++)
                o = fmaf(W3f[k * NH + n], a2[n], o);
            if (k == 3) o = tanhf_fast(o);
            out[(size_t)k * (size_t)B + (size_t)i] = o;
        }
    }
}

extern "C" void kernel_launch(void* const* d_in, const int* in_sizes, int n_in,
                              void* d_out, int out_size, void* d_ws, size_t ws_size,
                              hipStream_t stream) {
    const float* x   = (const float*)d_in[0];
    const float* y   = (const float*)d_in[1];
    const float* t   = (const float*)d_in[2];
    const float* W1  = (const float*)d_in[3];
    const float* b1  = (const float*)d_in[4];
    const float* g1  = (const float*)d_in[5];
    const float* be1 = (const float*)d_in[6];
    const float* W2  = (const float*)d_in[7];
    const float* b2  = (const float*)d_in[8];
    const float* g2  = (const float*)d_in[9];
    const float* be2 = (const float*)d_in[10];
    const float* W3  = (const float*)d_in[11];
    const float* b3  = (const float*)d_in[12];
    float* out = (float*)d_out;
    int B = in_sizes[0];
    float invB = 1.0f / (float)B;

    // workspace layout (floats)
    float* ws     = (float*)d_ws;
    float* stats1 = ws;        // 100
    float* stats2 = ws + 100;  // 100
    float* W2f    = ws + 200;  // 500
    float* b2f    = ws + 700;  // 50
    float* W3f    = ws + 750;  // 50
    float* b3f    = ws + 800;  // 5

    hipMemsetAsync(ws, 0, 200 * sizeof(float), stream);

    pass1_stats<<<512, 256, 0, stream>>>(x, y, t, W1, b1, stats1, B);
    fold1<<<1, 64, 0, stream>>>(stats1, g1, be1, W2, b2, W2f, b2f, invB);
    pass2_stats<<<512, 256, 0, stream>>>(x, y, t, W1, b1, W2f, b2f, stats2, B);
    fold2<<<1, 64, 0, stream>>>(stats2, g2, be2, W3, b3, W3f, b3f, invB);
    pass3_out<<<2048, 256, 0, stream>>>(x, y, t, W1, b1, W2f, b2f, W3f, b3f, out, B);
}

// Round 2
// 247.624 us; speedup vs baseline: 8.5688x; 8.5688x over previous
//
#include <hip/hip_runtime.h>
#include <hip/hip_bf16.h>

#define KB 5
#define NH 10
#define BN_EPS 1e-5f

__device__ __forceinline__ float sigmoidf_fast(float z) {
    float e = __builtin_amdgcn_exp2f(-1.442695040888963f * z);
    return __builtin_amdgcn_rcpf(1.0f + e);
}

__device__ __forceinline__ float tanhf_fast(float z) {
    float e = __builtin_amdgcn_exp2f(2.885390081777927f * z);
    return 1.0f - 2.0f * __builtin_amdgcn_rcpf(e + 1.0f);
}

// wave butterfly + LDS block reduce + one atomic per value per block
__device__ __forceinline__ void block_reduce_atomic(float* s, float* q, int k,
                                                    float* __restrict__ stats) {
    __shared__ float lds[4][2 * NH];
    int lane = threadIdx.x & 63, wave = threadIdx.x >> 6;
    #pragma unroll
    for (int n = 0; n < NH; n++) {
        float sv = s[n], qv = q[n];
        #pragma unroll
        for (int o = 32; o > 0; o >>= 1) {
            sv += __shfl_xor(sv, o);
            qv += __shfl_xor(qv, o);
        }
        if (lane == 0) { lds[wave][n] = sv; lds[wave][NH + n] = qv; }
    }
    __syncthreads();
    int tid = threadIdx.x;
    if (tid < 2 * NH) {
        float v = lds[0][tid] + lds[1][tid] + lds[2][tid] + lds[3][tid];
        int n = (tid < NH) ? tid : tid - NH;
        float* dst = (tid < NH) ? &stats[k * NH + n] : &stats[KB * NH + k * NH + n];
        atomicAdd(dst, v);
    }
}

// ---------------- pass 1: stats of a1 = sigmoid(W1*in + b1); k = blockIdx.y ----
__global__ __launch_bounds__(256) void pass1_stats(
    const float4* __restrict__ x4, const float4* __restrict__ y4, const float4* __restrict__ t4,
    const float* __restrict__ W1, const float* __restrict__ b1,
    float* __restrict__ stats1, int nvec) {
    int k = blockIdx.y;
    float w1[NH][3], bb1[NH];
    #pragma unroll
    for (int n = 0; n < NH; n++) {
        w1[n][0] = W1[(k * NH + n) * 3 + 0];
        w1[n][1] = W1[(k * NH + n) * 3 + 1];
        w1[n][2] = W1[(k * NH + n) * 3 + 2];
        bb1[n] = b1[k * NH + n];
    }
    float s[NH], q[NH];
    #pragma unroll
    for (int n = 0; n < NH; n++) { s[n] = 0.f; q[n] = 0.f; }

    int stride = gridDim.x * blockDim.x;
    #pragma unroll 1
    for (int i = blockIdx.x * blockDim.x + threadIdx.x; i < nvec; i += stride) {
        float4 xv = x4[i], yv = y4[i], tv = t4[i];
        float ex[4] = {xv.x, xv.y, xv.z, xv.w};
        float ey[4] = {yv.x, yv.y, yv.z, yv.w};
        float et[4] = {tv.x, tv.y, tv.z, tv.w};
        #pragma unroll
        for (int e = 0; e < 4; e++) {
            #pragma unroll
            for (int n = 0; n < NH; n++) {
                float z = fmaf(w1[n][0], ex[e], fmaf(w1[n][1], ey[e], fmaf(w1[n][2], et[e], bb1[n])));
                float a = sigmoidf_fast(z);
                s[n] += a;
                q[n] = fmaf(a, a, q[n]);
            }
        }
    }
    block_reduce_atomic(s, q, k, stats1);
}

// ---------------- fold 1: BN1 folded into W2 -> W2f, b2f ----------------
__global__ void fold1(const float* __restrict__ stats1,
                      const float* __restrict__ g1, const float* __restrict__ be1,
                      const float* __restrict__ W2, const float* __restrict__ b2,
                      float* __restrict__ W2f, float* __restrict__ b2f, float invB) {
    __shared__ float alpha[KB * NH], beta[KB * NH];
    int tid = threadIdx.x;
    if (tid < KB * NH) {
        float m = stats1[tid] * invB;
        float var = stats1[KB * NH + tid] * invB - m * m;
        float rstd = rsqrtf(var + BN_EPS);
        float a = g1[tid] * rstd;
        alpha[tid] = a;
        beta[tid] = be1[tid] - a * m;
    }
    __syncthreads();
    if (tid < KB * NH) {  // tid = k*NH + m
        int k = tid / NH;
        float acc = b2[tid];
        #pragma unroll
        for (int n = 0; n < NH; n++) {
            float w = W2[tid * NH + n];
            W2f[tid * NH + n] = w * alpha[k * NH + n];
            acc = fmaf(w, beta[k * NH + n], acc);
        }
        b2f[tid] = acc;
    }
}

// ---------------- pass 2: stats of a2; k = blockIdx.y ----------------
__global__ __launch_bounds__(256) void pass2_stats(
    const float4* __restrict__ x4, const float4* __restrict__ y4, const float4* __restrict__ t4,
    const float* __restrict__ W1, const float* __restrict__ b1,
    const float* __restrict__ W2f, const float* __restrict__ b2f,
    float* __restrict__ stats2, int nvec) {
    int k = blockIdx.y;
    float w1[NH][3], bb1[NH], w2[NH][NH], bb2[NH];
    #pragma unroll
    for (int n = 0; n < NH; n++) {
        w1[n][0] = W1[(k * NH + n) * 3 + 0];
        w1[n][1] = W1[(k * NH + n) * 3 + 1];
        w1[n][2] = W1[(k * NH + n) * 3 + 2];
        bb1[n] = b1[k * NH + n];
        bb2[n] = b2f[k * NH + n];
        #pragma unroll
        for (int m = 0; m < NH; m++)
            w2[n][m] = W2f[(k * NH + n) * NH + m];
    }
    float s[NH], q[NH];
    #pragma unroll
    for (int n = 0; n < NH; n++) { s[n] = 0.f; q[n] = 0.f; }

    int stride = gridDim.x * blockDim.x;
    #pragma unroll 1
    for (int i = blockIdx.x * blockDim.x + threadIdx.x; i < nvec; i += stride) {
        float4 xv = x4[i], yv = y4[i], tv = t4[i];
        float ex[4] = {xv.x, xv.y, xv.z, xv.w};
        float ey[4] = {yv.x, yv.y, yv.z, yv.w};
        float et[4] = {tv.x, tv.y, tv.z, tv.w};
        #pragma unroll
        for (int e = 0; e < 4; e++) {
            float a1[NH];
            #pragma unroll
            for (int n = 0; n < NH; n++) {
                float z = fmaf(w1[n][0], ex[e], fmaf(w1[n][1], ey[e], fmaf(w1[n][2], et[e], bb1[n])));
                a1[n] = sigmoidf_fast(z);
            }
            #pragma unroll
            for (int m = 0; m < NH; m++) {
                float z = bb2[m];
                #pragma unroll
                for (int n = 0; n < NH; n++)
                    z = fmaf(w2[m][n], a1[n], z);
                float a = sigmoidf_fast(z);
                s[m] += a;
                q[m] = fmaf(a, a, q[m]);
            }
        }
    }
    block_reduce_atomic(s, q, k, stats2);
}

// ---------------- fold 2: BN2 folded into W3 -> W3f, b3f ----------------
__global__ void fold2(const float* __restrict__ stats2,
                      const float* __restrict__ g2, const float* __restrict__ be2,
                      const float* __restrict__ W3, const float* __restrict__ b3,
                      float* __restrict__ W3f, float* __restrict__ b3f, float invB) {
    __shared__ float beta[KB * NH];
    int tid = threadIdx.x;
    if (tid < KB * NH) {
        float m = stats2[tid] * invB;
        float var = stats2[KB * NH + tid] * invB - m * m;
        float rstd = rsqrtf(var + BN_EPS);
        float al = g2[tid] * rstd;
        beta[tid] = be2[tid] - al * m;
        W3f[tid] = W3[tid] * al;   // W3 is [K,1,N] -> flat [K*N]
    }
    __syncthreads();
    if (tid < KB) {
        float acc = b3[tid];
        #pragma unroll
        for (int n = 0; n < NH; n++)
            acc = fmaf(W3[tid * NH + n], beta[tid * NH + n], acc);
        b3f[tid] = acc;
    }
}

// ---------------- pass 3: full forward + output; k = blockIdx.y ----------------
__global__ __launch_bounds__(256) void pass3_out(
    const float4* __restrict__ x4, const float4* __restrict__ y4, const float4* __restrict__ t4,
    const float* __restrict__ W1, const float* __restrict__ b1,
    const float* __restrict__ W2f, const float* __restrict__ b2f,
    const float* __restrict__ W3f, const float* __restrict__ b3f,
    float4* __restrict__ out4, int nvec) {
    int k = blockIdx.y;
    float w1[NH][3], bb1[NH], w2[NH][NH], bb2[NH], w3[NH];
    #pragma unroll
    for (int n = 0; n < NH; n++) {
        w1[n][0] = W1[(k * NH + n) * 3 + 0];
        w1[n][1] = W1[(k * NH + n) * 3 + 1];
        w1[n][2] = W1[(k * NH + n) * 3 + 2];
        bb1[n] = b1[k * NH + n];
        bb2[n] = b2f[k * NH + n];
        w3[n]  = W3f[k * NH + n];
        #pragma unroll
        for (int m = 0; m < NH; m++)
            w2[n][m] = W2f[(k * NH + n) * NH + m];
    }
    float bb3 = b3f[k];

    int stride = gridDim.x * blockDim.x;
    #pragma unroll 1
    for (int i = blockIdx.x * blockDim.x + threadIdx.x; i < nvec; i += stride) {
        float4 xv = x4[i], yv = y4[i], tv = t4[i];
        float ex[4] = {xv.x, xv.y, xv.z, xv.w};
        float ey[4] = {yv.x, yv.y, yv.z, yv.w};
        float et[4] = {tv.x, tv.y, tv.z, tv.w};
        float o[4];
        #pragma unroll
        for (int e = 0; e < 4; e++) {
            float a1[NH];
            #pragma unroll
            for (int n = 0; n < NH; n++) {
                float z = fmaf(w1[n][0], ex[e], fmaf(w1[n][1], ey[e], fmaf(w1[n][2], et[e], bb1[n])));
                a1[n] = sigmoidf_fast(z);
            }
            float acc = bb3;
            #pragma unroll
            for (int m = 0; m < NH; m++) {
                float z = bb2[m];
                #pragma unroll
                for (int n = 0; n < NH; n++)
                    z = fmaf(w2[m][n], a1[n], z);
                acc = fmaf(w3[m], sigmoidf_fast(z), acc);
            }
            o[e] = acc;
        }
        if (k == 3) {
            #pragma unroll
            for (int e = 0; e < 4; e++) o[e] = tanhf_fast(o[e]);
        }
        out4[(size_t)k * (size_t)nvec + (size_t)i] = make_float4(o[0], o[1], o[2], o[3]);
    }
}

extern "C" void kernel_launch(void* const* d_in, const int* in_sizes, int n_in,
                              void* d_out, int out_size, void* d_ws, size_t ws_size,
                              hipStream_t stream) {
    const float* x   = (const float*)d_in[0];
    const float* y   = (const float*)d_in[1];
    const float* t   = (const float*)d_in[2];
    const float* W1  = (const float*)d_in[3];
    const float* b1  = (const float*)d_in[4];
    const float* g1  = (const float*)d_in[5];
    const float* be1 = (const float*)d_in[6];
    const float* W2  = (const float*)d_in[7];
    const float* b2  = (const float*)d_in[8];
    const float* g2  = (const float*)d_in[9];
    const float* be2 = (const float*)d_in[10];
    const float* W3  = (const float*)d_in[11];
    const float* b3  = (const float*)d_in[12];
    float* out = (float*)d_out;
    int B = in_sizes[0];
    int nvec = B / 4;
    float invB = 1.0f / (float)B;

    // workspace layout (floats)
    float* ws     = (float*)d_ws;
    float* stats1 = ws;        // 100
    float* stats2 = ws + 100;  // 100
    float* W2f    = ws + 200;  // 500
    float* b2f    = ws + 700;  // 50
    float* W3f    = ws + 750;  // 50
    float* b3f    = ws + 800;  // 5

    hipMemsetAsync(ws, 0, 200 * sizeof(float), stream);

    const float4* x4 = (const float4*)x;
    const float4* y4 = (const float4*)y;
    const float4* t4 = (const float4*)t;

    pass1_stats<<<dim3(512, KB), 256, 0, stream>>>(x4, y4, t4, W1, b1, stats1, nvec);
    fold1<<<1, 64, 0, stream>>>(stats1, g1, be1, W2, b2, W2f, b2f, invB);
    pass2_stats<<<dim3(1024, KB), 256, 0, stream>>>(x4, y4, t4, W1, b1, W2f, b2f, stats2, nvec);
    fold2<<<1, 64, 0, stream>>>(stats2, g2, be2, W3, b3, W3f, b3f, invB);
    pass3_out<<<dim3(2048, KB), 256, 0, stream>>>(x4, y4, t4, W1, b1, W2f, b2f, W3f, b3f,
                                                  (float4*)out, nvec);
}

// Round 3
// 221.129 us; speedup vs baseline: 9.5955x; 1.1198x over previous
//
#include <hip/hip_runtime.h>
#include <hip/hip_bf16.h>

#define KB 5
#define NH 10
#define BN_EPS 1e-5f
#define C_LOG2E 1.442695040888963f

// activation on pre-scaled input: zs = -log2(e)*z  ->  sigmoid(z) = 1/(1+2^zs)
__device__ __forceinline__ float act_scaled(float zs) {
    return __builtin_amdgcn_rcpf(1.0f + __builtin_amdgcn_exp2f(zs));
}

__device__ __forceinline__ float tanhf_fast(float z) {
    float e = __builtin_amdgcn_exp2f(2.0f * C_LOG2E * z);
    return 1.0f - 2.0f * __builtin_amdgcn_rcpf(e + 1.0f);
}

// wave butterfly + LDS block reduce + one atomic per value per block
__device__ __forceinline__ void block_reduce_atomic(float* s, float* q, int k,
                                                    float* __restrict__ stats) {
    __shared__ float lds[4][2 * NH];
    int lane = threadIdx.x & 63, wave = threadIdx.x >> 6;
    #pragma unroll
    for (int n = 0; n < NH; n++) {
        float sv = s[n], qv = q[n];
        #pragma unroll
        for (int o = 32; o > 0; o >>= 1) {
            sv += __shfl_xor(sv, o);
            qv += __shfl_xor(qv, o);
        }
        if (lane == 0) { lds[wave][n] = sv; lds[wave][NH + n] = qv; }
    }
    __syncthreads();
    int tid = threadIdx.x;
    if (tid < 2 * NH) {
        float v = lds[0][tid] + lds[1][tid] + lds[2][tid] + lds[3][tid];
        int n = (tid < NH) ? tid : tid - NH;
        float* dst = (tid < NH) ? &stats[k * NH + n] : &stats[KB * NH + k * NH + n];
        atomicAdd(dst, v);
    }
}

// ---------------- prep: scale W1,b1 by -log2(e) ----------------
__global__ void prep_scale(const float* __restrict__ W1, const float* __restrict__ b1,
                           float* __restrict__ W1s, float* __restrict__ b1s) {
    int tid = threadIdx.x;
    if (tid < KB * NH * 3) W1s[tid] = -C_LOG2E * W1[tid];
    if (tid < KB * NH)     b1s[tid] = -C_LOG2E * b1[tid];
}

// ---------------- pass 1: stats of a1; k = blockIdx.y ----------------
__global__ __launch_bounds__(256) void pass1_stats(
    const float4* __restrict__ x4, const float4* __restrict__ y4, const float4* __restrict__ t4,
    const float* __restrict__ W1s, const float* __restrict__ b1s,
    float* __restrict__ stats1, int nvec) {
    int k = blockIdx.y;
    float w1[NH][3], bb1[NH];
    #pragma unroll
    for (int n = 0; n < NH; n++) {
        w1[n][0] = W1s[(k * NH + n) * 3 + 0];
        w1[n][1] = W1s[(k * NH + n) * 3 + 1];
        w1[n][2] = W1s[(k * NH + n) * 3 + 2];
        bb1[n] = b1s[k * NH + n];
    }
    float s[NH], q[NH];
    #pragma unroll
    for (int n = 0; n < NH; n++) { s[n] = 0.f; q[n] = 0.f; }

    int stride = gridDim.x * blockDim.x;
    #pragma unroll 1
    for (int i = blockIdx.x * blockDim.x + threadIdx.x; i < nvec; i += stride) {
        float4 xv = x4[i], yv = y4[i], tv = t4[i];
        #pragma unroll
        for (int e = 0; e < 4; e++) {
            float X = (e == 0) ? xv.x : (e == 1) ? xv.y : (e == 2) ? xv.z : xv.w;
            float Y = (e == 0) ? yv.x : (e == 1) ? yv.y : (e == 2) ? yv.z : yv.w;
            float T = (e == 0) ? tv.x : (e == 1) ? tv.y : (e == 2) ? tv.z : tv.w;
            #pragma unroll
            for (int n = 0; n < NH; n++) {
                float zs = fmaf(w1[n][0], X, fmaf(w1[n][1], Y, fmaf(w1[n][2], T, bb1[n])));
                float a = act_scaled(zs);
                s[n] += a;
                q[n] = fmaf(a, a, q[n]);
            }
        }
    }
    block_reduce_atomic(s, q, k, stats1);
}

// ---------------- fold 1: BN1 folded into W2 -> W2s, b2s (scaled by -log2e) ----
__global__ void fold1(const float* __restrict__ stats1,
                      const float* __restrict__ g1, const float* __restrict__ be1,
                      const float* __restrict__ W2, const float* __restrict__ b2,
                      float* __restrict__ W2s, float* __restrict__ b2s, float invB) {
    __shared__ float alpha[KB * NH], beta[KB * NH];
    int tid = threadIdx.x;
    if (tid < KB * NH) {
        float m = stats1[tid] * invB;
        float var = stats1[KB * NH + tid] * invB - m * m;
        float rstd = rsqrtf(var + BN_EPS);
        float a = g1[tid] * rstd;
        alpha[tid] = a;
        beta[tid] = be1[tid] - a * m;
    }
    __syncthreads();
    if (tid < KB * NH) {  // tid = k*NH + m
        int k = tid / NH;
        float acc = b2[tid];
        #pragma unroll
        for (int n = 0; n < NH; n++) {
            float w = W2[tid * NH + n];
            W2s[tid * NH + n] = -C_LOG2E * w * alpha[k * NH + n];
            acc = fmaf(w, beta[k * NH + n], acc);
        }
        b2s[tid] = -C_LOG2E * acc;
    }
}

// ---------------- pass 2: stats of a2; k = blockIdx.y ----------------
__global__ __launch_bounds__(256) void pass2_stats(
    const float4* __restrict__ x4, const float4* __restrict__ y4, const float4* __restrict__ t4,
    const float* __restrict__ W1s, const float* __restrict__ b1s,
    const float* __restrict__ W2s, const float* __restrict__ b2s,
    float* __restrict__ stats2, int nvec) {
    int k = blockIdx.y;
    float w1[NH][3], bb1[NH], w2[NH][NH], bb2[NH];
    #pragma unroll
    for (int n = 0; n < NH; n++) {
        w1[n][0] = W1s[(k * NH + n) * 3 + 0];
        w1[n][1] = W1s[(k * NH + n) * 3 + 1];
        w1[n][2] = W1s[(k * NH + n) * 3 + 2];
        bb1[n] = b1s[k * NH + n];
        bb2[n] = b2s[k * NH + n];
        #pragma unroll
        for (int m = 0; m < NH; m++)
            w2[n][m] = W2s[(k * NH + n) * NH + m];
    }
    float s[NH], q[NH];
    #pragma unroll
    for (int n = 0; n < NH; n++) { s[n] = 0.f; q[n] = 0.f; }

    int stride = gridDim.x * blockDim.x;
    #pragma unroll 1
    for (int i = blockIdx.x * blockDim.x + threadIdx.x; i < nvec; i += stride) {
        float4 xv = x4[i], yv = y4[i], tv = t4[i];
        #pragma unroll
        for (int e = 0; e < 4; e++) {
            float X = (e == 0) ? xv.x : (e == 1) ? xv.y : (e == 2) ? xv.z : xv.w;
            float Y = (e == 0) ? yv.x : (e == 1) ? yv.y : (e == 2) ? yv.z : yv.w;
            float T = (e == 0) ? tv.x : (e == 1) ? tv.y : (e == 2) ? tv.z : tv.w;
            float a1[NH];
            #pragma unroll
            for (int n = 0; n < NH; n++) {
                float zs = fmaf(w1[n][0], X, fmaf(w1[n][1], Y, fmaf(w1[n][2], T, bb1[n])));
                a1[n] = act_scaled(zs);
            }
            #pragma unroll
            for (int m = 0; m < NH; m++) {
                float z = bb2[m];
                #pragma unroll
                for (int n = 0; n < NH; n++)
                    z = fmaf(w2[m][n], a1[n], z);
                float a = act_scaled(z);
                s[m] += a;
                q[m] = fmaf(a, a, q[m]);
            }
        }
    }
    block_reduce_atomic(s, q, k, stats2);
}

// ---------------- fold 2: BN2 folded into W3 -> W3f, b3f ----------------
__global__ void fold2(const float* __restrict__ stats2,
                      const float* __restrict__ g2, const float* __restrict__ be2,
                      const float* __restrict__ W3, const float* __restrict__ b3,
                      float* __restrict__ W3f, float* __restrict__ b3f, float invB) {
    __shared__ float beta[KB * NH];
    int tid = threadIdx.x;
    if (tid < KB * NH) {
        float m = stats2[tid] * invB;
        float var = stats2[KB * NH + tid] * invB - m * m;
        float rstd = rsqrtf(var + BN_EPS);
        float al = g2[tid] * rstd;
        beta[tid] = be2[tid] - al * m;
        W3f[tid] = W3[tid] * al;   // W3 is [K,1,N] -> flat [K*N]
    }
    __syncthreads();
    if (tid < KB) {
        float acc = b3[tid];
        #pragma unroll
        for (int n = 0; n < NH; n++)
            acc = fmaf(W3[tid * NH + n], beta[tid * NH + n], acc);
        b3f[tid] = acc;
    }
}

// ---------------- pass 3: full forward + output; k = blockIdx.y ----------------
__global__ __launch_bounds__(256) void pass3_out(
    const float4* __restrict__ x4, const float4* __restrict__ y4, const float4* __restrict__ t4,
    const float* __restrict__ W1s, const float* __restrict__ b1s,
    const float* __restrict__ W2s, const float* __restrict__ b2s,
    const float* __restrict__ W3f, const float* __restrict__ b3f,
    float4* __restrict__ out4, int nvec) {
    int k = blockIdx.y;
    float w1[NH][3], bb1[NH], w2[NH][NH], bb2[NH], w3[NH];
    #pragma unroll
    for (int n = 0; n < NH; n++) {
        w1[n][0] = W1s[(k * NH + n) * 3 + 0];
        w1[n][1] = W1s[(k * NH + n) * 3 + 1];
        w1[n][2] = W1s[(k * NH + n) * 3 + 2];
        bb1[n] = b1s[k * NH + n];
        bb2[n] = b2s[k * NH + n];
        w3[n]  = W3f[k * NH + n];
        #pragma unroll
        for (int m = 0; m < NH; m++)
            w2[n][m] = W2s[(k * NH + n) * NH + m];
    }
    float bb3 = b3f[k];

    int stride = gridDim.x * blockDim.x;
    #pragma unroll 1
    for (int i = blockIdx.x * blockDim.x + threadIdx.x; i < nvec; i += stride) {
        float4 xv = x4[i], yv = y4[i], tv = t4[i];
        float o[4];
        #pragma unroll
        for (int e = 0; e < 4; e++) {
            float X = (e == 0) ? xv.x : (e == 1) ? xv.y : (e == 2) ? xv.z : xv.w;
            float Y = (e == 0) ? yv.x : (e == 1) ? yv.y : (e == 2) ? yv.z : yv.w;
            float T = (e == 0) ? tv.x : (e == 1) ? tv.y : (e == 2) ? tv.z : tv.w;
            float a1[NH];
            #pragma unroll
            for (int n = 0; n < NH; n++) {
                float zs = fmaf(w1[n][0], X, fmaf(w1[n][1], Y, fmaf(w1[n][2], T, bb1[n])));
                a1[n] = act_scaled(zs);
            }
            float acc = bb3;
            #pragma unroll
            for (int m = 0; m < NH; m++) {
                float z = bb2[m];
                #pragma unroll
                for (int n = 0; n < NH; n++)
                    z = fmaf(w2[m][n], a1[n], z);
                acc = fmaf(w3[m], act_scaled(z), acc);
            }
            o[e] = acc;
        }
        if (k == 3) {
            #pragma unroll
            for (int e = 0; e < 4; e++) o[e] = tanhf_fast(o[e]);
        }
        out4[(size_t)k * (size_t)nvec + (size_t)i] = make_float4(o[0], o[1], o[2], o[3]);
    }
}

extern "C" void kernel_launch(void* const* d_in, const int* in_sizes, int n_in,
                              void* d_out, int out_size, void* d_ws, size_t ws_size,
                              hipStream_t stream) {
    const float* x   = (const float*)d_in[0];
    const float* y   = (const float*)d_in[1];
    const float* t   = (const float*)d_in[2];
    const float* W1  = (const float*)d_in[3];
    const float* b1  = (const float*)d_in[4];
    const float* g1  = (const float*)d_in[5];
    const float* be1 = (const float*)d_in[6];
    const float* W2  = (const float*)d_in[7];
    const float* b2  = (const float*)d_in[8];
    const float* g2  = (const float*)d_in[9];
    const float* be2 = (const float*)d_in[10];
    const float* W3  = (const float*)d_in[11];
    const float* b3  = (const float*)d_in[12];
    float* out = (float*)d_out;
    int B = in_sizes[0];
    int nvec = B / 4;
    float invB = 1.0f / (float)B;

    // workspace layout (floats)
    float* ws     = (float*)d_ws;
    float* stats1 = ws;         // 100
    float* stats2 = ws + 100;   // 100
    float* W1s    = ws + 200;   // 150
    float* b1s    = ws + 350;   // 50
    float* W2s    = ws + 400;   // 500
    float* b2s    = ws + 900;   // 50
    float* W3f    = ws + 950;   // 50
    float* b3f    = ws + 1000;  // 5

    hipMemsetAsync(ws, 0, 200 * sizeof(float), stream);

    const float4* x4 = (const float4*)x;
    const float4* y4 = (const float4*)y;
    const float4* t4 = (const float4*)t;

    prep_scale<<<1, 256, 0, stream>>>(W1, b1, W1s, b1s);
    pass1_stats<<<dim3(256, KB), 256, 0, stream>>>(x4, y4, t4, W1s, b1s, stats1, nvec);
    fold1<<<1, 64, 0, stream>>>(stats1, g1, be1, W2, b2, W2s, b2s, invB);
    pass2_stats<<<dim3(512, KB), 256, 0, stream>>>(x4, y4, t4, W1s, b1s, W2s, b2s, stats2, nvec);
    fold2<<<1, 64, 0, stream>>>(stats2, g2, be2, W3, b3, W3f, b3f, invB);
    pass3_out<<<dim3(512, KB), 256, 0, stream>>>(x4, y4, t4, W1s, b1s, W2s, b2s, W3f, b3f,
                                                 (float4*)out, nvec);
}